// Round 6
// baseline (83.568 us; speedup 1.0000x reference)
//
#include <hip/hip_runtime.h>
#include <math.h>

typedef __attribute__((ext_vector_type(8))) short bf16x8;
typedef __attribute__((ext_vector_type(4))) float f32x4;

static __device__ __forceinline__ unsigned short f2bf(float f) {
  union { float f; unsigned u; } a; a.f = f;
  unsigned u = a.u;
  unsigned r = u + 0x7FFF + ((u >> 16) & 1);   // RNE
  return (unsigned short)(r >> 16);
}
static __device__ __forceinline__ float bf2f(unsigned short h) {
  union { unsigned u; float f; } a; a.u = ((unsigned)h) << 16;
  return a.f;
}
static __device__ __forceinline__ float tanh_fast(float x) {
  float ax = fabsf(x);
  float e = __expf(-2.0f * ax);
  float t = (1.0f - e) / (1.0f + e);
  t = (ax > 10.0f) ? 1.0f : t;
  return (x < 0.0f) ? -t : t;
}

// async 16B global -> LDS (wave-uniform LDS base + lane*16; global addr per-lane)
static __device__ __forceinline__ void gload16(const void* g, void* l) {
  __builtin_amdgcn_global_load_lds(
      (const __attribute__((address_space(1))) unsigned int*)g,
      (__attribute__((address_space(3))) unsigned int*)l, 16, 0, 0);
}

// Blocks 0..143: 64x64 LDS-transpose tiles of W1/W2/Wv -> WT hi/lo (coalesced R+W).
// Blocks 144..1167: elementwise split of x -> Xh/Xl.
__global__ __launch_bounds__(256) void k_split_all(
    const float* __restrict__ W1, const float* __restrict__ W2,
    const float* __restrict__ Wv, const float* __restrict__ X,
    unsigned short* __restrict__ W1Th, unsigned short* __restrict__ W1Tl,
    unsigned short* __restrict__ W2Th, unsigned short* __restrict__ W2Tl,
    unsigned short* __restrict__ WvTh, unsigned short* __restrict__ WvTl,
    unsigned short* __restrict__ Xh,  unsigned short* __restrict__ Xl)
{
  const int b = blockIdx.x, t = threadIdx.x;
  if (b >= 144) {
    const size_t i0 = (size_t)(b - 144) * 2048 + (size_t)t * 8;
    const float4 v0 = *reinterpret_cast<const float4*>(&X[i0]);
    const float4 v1 = *reinterpret_cast<const float4*>(&X[i0 + 4]);
    const float vv[8] = {v0.x, v0.y, v0.z, v0.w, v1.x, v1.y, v1.z, v1.w};
    uint4 hp, lp;
    unsigned hw[4], lw[4];
#pragma unroll
    for (int e = 0; e < 4; ++e) {
      const unsigned short h0 = f2bf(vv[2*e]), h1 = f2bf(vv[2*e+1]);
      hw[e] = (unsigned)h0 | ((unsigned)h1 << 16);
      lw[e] = (unsigned)f2bf(vv[2*e] - bf2f(h0)) |
              ((unsigned)f2bf(vv[2*e+1] - bf2f(h1)) << 16);
    }
    hp.x = hw[0]; hp.y = hw[1]; hp.z = hw[2]; hp.w = hw[3];
    lp.x = lw[0]; lp.y = lw[1]; lp.z = lw[2]; lp.w = lw[3];
    *reinterpret_cast<uint4*>(&Xh[i0]) = hp;
    *reinterpret_cast<uint4*>(&Xl[i0]) = lp;
    return;
  }

  __shared__ unsigned short shh[64 * 72], shl[64 * 72];  // [n][k], pitch 72 (144B: 16B-aligned rows)
  const float* W; unsigned short *Th, *Tl; int Kd, Nd, k0, n0;
  if (b < 64)       { W = W1; Th = W1Th; Tl = W1Tl; Kd = 256;  Nd = 1024; k0 = (b & 3) * 64;        n0 = (b >> 2) * 64; }
  else if (b < 128) { W = W2; Th = W2Th; Tl = W2Tl; Kd = 1024; Nd = 256;  k0 = ((b - 64) & 15) * 64; n0 = ((b - 64) >> 4) * 64; }
  else              { W = Wv; Th = WvTh; Tl = WvTl; Kd = 256;  Nd = 256;  k0 = ((b - 128) & 3) * 64; n0 = ((b - 128) >> 2) * 64; }

  const int kloc = t >> 4, n4 = t & 15;
#pragma unroll
  for (int p = 0; p < 4; ++p) {
    const int kk = p * 16 + kloc;
    const float4 v = *reinterpret_cast<const float4*>(&W[(size_t)(k0 + kk) * Nd + n0 + n4 * 4]);
    const float vv[4] = {v.x, v.y, v.z, v.w};
#pragma unroll
    for (int e = 0; e < 4; ++e) {
      const unsigned short hh = f2bf(vv[e]);
      shh[(n4 * 4 + e) * 72 + kk] = hh;
      shl[(n4 * 4 + e) * 72 + kk] = f2bf(vv[e] - bf2f(hh));
    }
  }
  __syncthreads();
  const int nl = t >> 2, ko = (t & 3) * 16;
  const size_t dst = (size_t)(n0 + nl) * Kd + k0 + ko;
  *reinterpret_cast<uint4*>(&Th[dst])     = *reinterpret_cast<const uint4*>(&shh[nl * 72 + ko]);
  *reinterpret_cast<uint4*>(&Th[dst + 8]) = *reinterpret_cast<const uint4*>(&shh[nl * 72 + ko + 8]);
  *reinterpret_cast<uint4*>(&Tl[dst])     = *reinterpret_cast<const uint4*>(&shl[nl * 72 + ko]);
  *reinterpret_cast<uint4*>(&Tl[dst + 8]) = *reinterpret_cast<const uint4*>(&shl[nl * 72 + ko + 8]);
}

// GEMM1: H = tanh(x @ W1 + b1).  M=8192 K=256 N=1024.
// 128x128 tile, BK=32, 4 waves (wave-tile 64x64).  All staging via global_load_lds(16B)
// with source-swizzled addresses; LDS linear [128][32]-bf16 per array (64B rows).
// Swizzle: logical (row,g) stored at byte row*64 + ((g ^ ((row>>1)&3))<<4).
__global__ __launch_bounds__(256, 2) void k_gemm1(
    const unsigned short* __restrict__ Xh, const unsigned short* __restrict__ Xl,
    const unsigned short* __restrict__ BTh, const unsigned short* __restrict__ BTl,
    const float* __restrict__ bias,
    unsigned short* __restrict__ Hh, unsigned short* __restrict__ Hl)
{
  __shared__ unsigned short lds[16384];  // bytes: Ah@0  Al@8192  Bh@16384  Bl@24576
  const int t = threadIdx.x, l = t & 63, wv = t >> 6;
  const int n0 = blockIdx.x * 128, m0 = blockIdx.y * 128;
  const int wr = wv >> 1, wc = wv & 1;

  // staging: wave wv owns one array (0:Ah from Xh, 1:Al from Xl, 2:Bh from W1Th, 3:Bl from W1Tl)
  const unsigned short* ssrc = (wv == 0) ? Xh : (wv == 1) ? Xl : (wv == 2) ? BTh : BTl;
  const int rbase = (wv < 2) ? m0 : n0;
  char* ldsb = (char*)lds + wv * 8192;
  const int srow = l >> 2;                       // + c*16
  const int sg = (l & 3) ^ ((l >> 3) & 3);       // inverse-swizzled source col-group

  const int gofs = ((l >> 4) ^ ((l >> 1) & 3)) << 4;   // swizzled read col-offset
  const int arow = wr * 64 + (l & 15), brow = wc * 64 + (l & 15);

  f32x4 acc[4][4] = {};
  for (int k0 = 0; k0 < 256; k0 += 32) {
#pragma unroll
    for (int c = 0; c < 8; ++c)
      gload16(ssrc + (size_t)(rbase + c * 16 + srow) * 256 + k0 + sg * 8, ldsb + c * 1024);
    __syncthreads();

    const char* L = (const char*)lds;
    bf16x8 ah[4], al[4], bh[4], bl[4];
#pragma unroll
    for (int i = 0; i < 4; ++i) {
      ah[i] = *reinterpret_cast<const bf16x8*>(L +         (arow + i * 16) * 64 + gofs);
      al[i] = *reinterpret_cast<const bf16x8*>(L +  8192 + (arow + i * 16) * 64 + gofs);
      bh[i] = *reinterpret_cast<const bf16x8*>(L + 16384 + (brow + i * 16) * 64 + gofs);
      bl[i] = *reinterpret_cast<const bf16x8*>(L + 24576 + (brow + i * 16) * 64 + gofs);
    }
#pragma unroll
    for (int i = 0; i < 4; ++i)
#pragma unroll
      for (int j = 0; j < 4; ++j) {
        acc[i][j] = __builtin_amdgcn_mfma_f32_16x16x32_bf16(ah[i], bh[j], acc[i][j], 0, 0, 0);
        acc[i][j] = __builtin_amdgcn_mfma_f32_16x16x32_bf16(ah[i], bl[j], acc[i][j], 0, 0, 0);
        acc[i][j] = __builtin_amdgcn_mfma_f32_16x16x32_bf16(al[i], bh[j], acc[i][j], 0, 0, 0);
      }
    __syncthreads();
  }

#pragma unroll
  for (int i = 0; i < 4; ++i)
#pragma unroll
    for (int j = 0; j < 4; ++j) {
      const int gn = n0 + wc * 64 + j * 16 + (l & 15);
      const float bv = bias[gn];
#pragma unroll
      for (int r = 0; r < 4; ++r) {
        const int gm = m0 + wr * 64 + i * 16 + (l >> 4) * 4 + r;
        const float tv = tanh_fast(acc[i][j][r] + bv);
        const unsigned short th = f2bf(tv);
        Hh[(size_t)gm * 1024 + gn] = th;
        Hl[(size_t)gm * 1024 + gn] = f2bf(tv - bf2f(th));
      }
    }
}

// GEMM2: out = H @ W2 + b2 + x.  M=8192 K=1024 N=256.
// 64x128 tile, BK=64, 4 waves (wave-tile 32x64), grid (2,128)=256 blocks.
// LDS linear [rows][64]-bf16 (128B rows); swizzle byte ^= ((row&7)<<4).
__global__ __launch_bounds__(256, 2) void k_gemm2(
    const unsigned short* __restrict__ Ahg, const unsigned short* __restrict__ Alg,
    const unsigned short* __restrict__ BTh, const unsigned short* __restrict__ BTl,
    const float* __restrict__ bias, const float* __restrict__ X,
    float* __restrict__ OUT)
{
  __shared__ unsigned short lds[24576];  // bytes: Ah@0(8K) Al@8192 Bh@16384(16K) Bl@32768
  const int t = threadIdx.x, l = t & 63, wv = t >> 6;
  const int n0 = blockIdx.x * 128, m0 = blockIdx.y * 64;
  const int wr = wv >> 1, wc = wv & 1;
  const int srow8 = l >> 3, sg = (l & 7) ^ (l >> 3);

  f32x4 acc[2][4] = {};
  for (int k0 = 0; k0 < 1024; k0 += 64) {
#pragma unroll
    for (int s = 0; s < 12; ++s) {
      const int cid = wv * 12 + s;
      const unsigned short* src; int rbase, ca, cbyte;
      if (cid < 8)       { src = Ahg; rbase = m0; ca = cid;      cbyte = ca * 1024; }
      else if (cid < 16) { src = Alg; rbase = m0; ca = cid - 8;  cbyte = 8192 + ca * 1024; }
      else if (cid < 32) { src = BTh; rbase = n0; ca = cid - 16; cbyte = 16384 + ca * 1024; }
      else               { src = BTl; rbase = n0; ca = cid - 32; cbyte = 32768 + ca * 1024; }
      gload16(src + (size_t)(rbase + ca * 8 + srow8) * 1024 + k0 + sg * 8, (char*)lds + cbyte);
    }
    __syncthreads();

    const char* L = (const char*)lds;
#pragma unroll
    for (int ks = 0; ks < 2; ++ks) {
      const int gofs = (((ks * 4 + (l >> 4)) ^ (l & 7)) << 4);
      bf16x8 ah[2], al[2], bh[4], bl[4];
#pragma unroll
      for (int i = 0; i < 2; ++i) {
        const int r = wr * 32 + i * 16 + (l & 15);
        ah[i] = *reinterpret_cast<const bf16x8*>(L +        r * 128 + gofs);
        al[i] = *reinterpret_cast<const bf16x8*>(L + 8192 + r * 128 + gofs);
      }
#pragma unroll
      for (int j = 0; j < 4; ++j) {
        const int r = wc * 64 + j * 16 + (l & 15);
        bh[j] = *reinterpret_cast<const bf16x8*>(L + 16384 + r * 128 + gofs);
        bl[j] = *reinterpret_cast<const bf16x8*>(L + 32768 + r * 128 + gofs);
      }
#pragma unroll
      for (int i = 0; i < 2; ++i)
#pragma unroll
        for (int j = 0; j < 4; ++j) {
          acc[i][j] = __builtin_amdgcn_mfma_f32_16x16x32_bf16(ah[i], bh[j], acc[i][j], 0, 0, 0);
          acc[i][j] = __builtin_amdgcn_mfma_f32_16x16x32_bf16(ah[i], bl[j], acc[i][j], 0, 0, 0);
          acc[i][j] = __builtin_amdgcn_mfma_f32_16x16x32_bf16(al[i], bh[j], acc[i][j], 0, 0, 0);
        }
    }
    __syncthreads();
  }

#pragma unroll
  for (int i = 0; i < 2; ++i)
#pragma unroll
    for (int j = 0; j < 4; ++j) {
      const int gn = n0 + wc * 64 + j * 16 + (l & 15);
      const float bv = bias[gn];
#pragma unroll
      for (int r = 0; r < 4; ++r) {
        const int gm = m0 + wr * 32 + i * 16 + (l >> 4) * 4 + r;
        OUT[(size_t)gm * 256 + gn] = acc[i][j][r] + bv + X[(size_t)gm * 256 + gn];
      }
    }
}

// Fused V + alpha + rescale (unchanged from r5): Wv fragments in registers,
// 1 row-tile of 16 samples per block, grid 512, f32 square-reduce.
__global__ __launch_bounds__(512) void k_valpha(
    const float* __restrict__ X,
    const unsigned short* __restrict__ WvTh, const unsigned short* __restrict__ WvTl,
    float* __restrict__ F)
{
  __shared__ __align__(16) unsigned short Ash[32 * 256];
  __shared__ __align__(16) unsigned short Asl[32 * 256];
  __shared__ float part[2][16][8];
  __shared__ float als[16];
  const int t = threadIdx.x;
  const int l = t & 63, w = t >> 6;
  const int c = l & 15, g = l >> 4;
  const int nb = w * 32;

  bf16x8 bh[2][8], bl[2][8];
#pragma unroll
  for (int nf = 0; nf < 2; ++nf)
#pragma unroll
    for (int ks = 0; ks < 8; ++ks) {
      const int col = nb + nf * 16 + c;
      const int kof = ks * 32 + g * 8;
      bh[nf][ks] = *reinterpret_cast<const bf16x8*>(&WvTh[(size_t)col * 256 + kof]);
      bl[nf][ks] = *reinterpret_cast<const bf16x8*>(&WvTl[(size_t)col * 256 + kof]);
    }

  const int srow = t >> 4;
  const int q = t & 15;
  const int r0 = blockIdx.x * 16;

  float4 fv[4];
  {
    const float* src = (srow < 16) ? &X[(size_t)(r0 + srow) * 256]
                                   : &F[(size_t)(r0 + srow - 16) * 256];
#pragma unroll
    for (int i = 0; i < 4; ++i) {
      const float4 v = *reinterpret_cast<const float4*>(&src[q * 16 + i * 4]);
      fv[i] = v;
      const unsigned short h0 = f2bf(v.x), h1 = f2bf(v.y), h2 = f2bf(v.z), h3 = f2bf(v.w);
      uint2 hp, lp;
      hp.x = (unsigned)h0 | ((unsigned)h1 << 16);
      hp.y = (unsigned)h2 | ((unsigned)h3 << 16);
      lp.x = (unsigned)f2bf(v.x - bf2f(h0)) | ((unsigned)f2bf(v.y - bf2f(h1)) << 16);
      lp.y = (unsigned)f2bf(v.z - bf2f(h2)) | ((unsigned)f2bf(v.w - bf2f(h3)) << 16);
      const unsigned byte = (unsigned)(srow * 512 + q * 32 + i * 8) ^ ((srow & 7) << 4);
      *reinterpret_cast<uint2*>(((char*)Ash) + byte) = hp;
      *reinterpret_cast<uint2*>(((char*)Asl) + byte) = lp;
    }
  }
  __syncthreads();

  float vs[2][4] = {};
#pragma unroll
  for (int nf = 0; nf < 2; ++nf) {
    f32x4 acc0 = {}, acc1 = {};
#pragma unroll
    for (int ks = 0; ks < 8; ++ks) {
      const int kof = ks * 32 + g * 8;
      const unsigned ab0 = (unsigned)(c * 512 + kof * 2) ^ ((c & 7) << 4);
      const unsigned ab1 = (unsigned)((c + 16) * 512 + kof * 2) ^ ((c & 7) << 4);
      const bf16x8 a0h = *reinterpret_cast<const bf16x8*>(((char*)Ash) + ab0);
      const bf16x8 a0l = *reinterpret_cast<const bf16x8*>(((char*)Asl) + ab0);
      const bf16x8 a1h = *reinterpret_cast<const bf16x8*>(((char*)Ash) + ab1);
      const bf16x8 a1l = *reinterpret_cast<const bf16x8*>(((char*)Asl) + ab1);
      acc0 = __builtin_amdgcn_mfma_f32_16x16x32_bf16(a0h, bh[nf][ks], acc0, 0, 0, 0);
      acc0 = __builtin_amdgcn_mfma_f32_16x16x32_bf16(a0h, bl[nf][ks], acc0, 0, 0, 0);
      acc0 = __builtin_amdgcn_mfma_f32_16x16x32_bf16(a0l, bh[nf][ks], acc0, 0, 0, 0);
      acc1 = __builtin_amdgcn_mfma_f32_16x16x32_bf16(a1h, bh[nf][ks], acc1, 0, 0, 0);
      acc1 = __builtin_amdgcn_mfma_f32_16x16x32_bf16(a1h, bl[nf][ks], acc1, 0, 0, 0);
      acc1 = __builtin_amdgcn_mfma_f32_16x16x32_bf16(a1l, bh[nf][ks], acc1, 0, 0, 0);
    }
#pragma unroll
    for (int r = 0; r < 4; ++r) {
      vs[0][r] = fmaf(acc0[r], acc0[r], vs[0][r]);
      vs[1][r] = fmaf(acc1[r], acc1[r], vs[1][r]);
    }
  }

#pragma unroll
  for (int s = 0; s < 2; ++s)
#pragma unroll
    for (int r = 0; r < 4; ++r) {
      float v = vs[s][r];
      v += __shfl_xor(v, 1);
      v += __shfl_xor(v, 2);
      v += __shfl_xor(v, 4);
      v += __shfl_xor(v, 8);
      vs[s][r] = v;
    }
  if (c == 0) {
#pragma unroll
    for (int r = 0; r < 4; ++r) {
      part[0][g * 4 + r][w] = vs[0][r];
      part[1][g * 4 + r][w] = vs[1][r];
    }
  }
  __syncthreads();

  if (t < 16) {
    float Vx = 0.f, Vf = 0.f;
#pragma unroll
    for (int i = 0; i < 8; ++i) { Vx += part[0][t][i]; Vf += part[1][t][i]; }
    const float tt2 = 0.99f * Vx;
    float a;
    if (Vf - tt2 > 0.0f)         a = sqrtf(tt2 / Vf);   // Newton limit
    else if (tt2 - Vf > 1e-4f)   a = 0.5f;              // stuck-bisection case
    else                         a = 1.0f;              // never masked
    als[t] = a;
  }
  __syncthreads();

  if (srow >= 16) {
    const int row = srow - 16;
    const float a = als[row];
    float* dst = &F[(size_t)(r0 + row) * 256];
#pragma unroll
    for (int i = 0; i < 4; ++i) {
      float4 v = fv[i];
      v.x *= a; v.y *= a; v.z *= a; v.w *= a;
      *reinterpret_cast<float4*>(&dst[q * 16 + i * 4]) = v;
    }
  }
}

extern "C" void kernel_launch(void* const* d_in, const int* in_sizes, int n_in,
                              void* d_out, int out_size, void* d_ws, size_t ws_size,
                              hipStream_t stream) {
  const float* x  = (const float*)d_in[0];
  const float* W1 = (const float*)d_in[1];
  const float* b1 = (const float*)d_in[2];
  const float* W2 = (const float*)d_in[3];
  const float* b2 = (const float*)d_in[4];
  const float* Wv = (const float*)d_in[5];
  float* out = (float*)d_out;

  char* ws = (char*)d_ws;
  unsigned short* Hh   = (unsigned short*)(ws);                    // 16.8 MB
  unsigned short* Hl   = (unsigned short*)(ws + 16777216);         // 16.8 MB
  unsigned short* W1Th = (unsigned short*)(ws + 33554432);
  unsigned short* W1Tl = (unsigned short*)(ws + 34078720);
  unsigned short* W2Th = (unsigned short*)(ws + 34603008);
  unsigned short* W2Tl = (unsigned short*)(ws + 35127296);
  unsigned short* WvTh = (unsigned short*)(ws + 35651584);
  unsigned short* WvTl = (unsigned short*)(ws + 35782656);
  unsigned short* Xh   = (unsigned short*)(ws + 35913728);         // 4.2 MB
  unsigned short* Xl   = (unsigned short*)(ws + 40108032);         // 4.2 MB

  k_split_all<<<dim3(1168), dim3(256), 0, stream>>>(
      W1, W2, Wv, x, W1Th, W1Tl, W2Th, W2Tl, WvTh, WvTl, Xh, Xl);

  k_gemm1 <<<dim3(8, 64),  dim3(256), 0, stream>>>(Xh, Xl, W1Th, W1Tl, b1, Hh, Hl);
  k_gemm2 <<<dim3(2, 128), dim3(256), 0, stream>>>(Hh, Hl, W2Th, W2Tl, b2, x, out);
  k_valpha<<<dim3(512), dim3(512), 0, stream>>>(x, WvTh, WvTl, out);
}